// Round 3
// baseline (470.045 us; speedup 1.0000x reference)
//
#include <hip/hip_runtime.h>

#define H 16
#define S 2048
#define D 64
#define BM 64   // q-rows per block (16 per wave)
#define BN 64   // t per tile
#define KP 72   // LDS row pitch in bf16 elements (64 + 8 pad, 144B = 16B-aligned rows)

typedef __attribute__((ext_vector_type(8))) short bf16x8;
typedef __attribute__((ext_vector_type(4))) short short4v;
typedef __attribute__((ext_vector_type(4))) float fx4;

// fp32 -> bf16 bits, round-to-nearest-even
static __device__ __forceinline__ short f2bf(float x) {
    unsigned u = __float_as_uint(x);
    u += 0x7fffu + ((u >> 16) & 1u);
    return (short)(u >> 16);
}
static __device__ __forceinline__ float bf2f(short s) {
    return __uint_as_float(((unsigned)(unsigned short)s) << 16);
}

__global__ __launch_bounds__(256)
void ParallelRetention_origin_25374666785438_kernel(
    const float* __restrict__ q, const float* __restrict__ k,
    const float* __restrict__ v, const float* __restrict__ om,
    float* __restrict__ out)
{
    __shared__ short ldsKh[BN * KP];       // K tile hi, [t][d] bf16
    __shared__ short ldsKl[BN * KP];       // K tile lo (residual), [t][d] bf16
    __shared__ short ldsVT[D * KP];        // V tile transposed, [d][t] bf16
    __shared__ short ldsP[4 * 16 * KP];    // per-wave P round-trip, [row][t] bf16

    const int tid  = threadIdx.x;
    const int wave = tid >> 6;
    const int lane = tid & 63;
    const int col  = lane & 15;   // MFMA n-index / A-operand m-index
    const int quad = lane >> 4;   // 0..3

    // swizzle: consecutive blockIdx -> different heads; each XCD's hot K/V set = 2 heads = 2MB
    const int h  = blockIdx.x & 15;
    const int qb = blockIdx.x >> 4;      // 0..31
    const int row0 = qb * BM;

    const size_t headQK = (size_t)h * S * D;
    const size_t headM  = (size_t)h * S * S;

    // ---- load Q A-fragments once, split hi+lo: A[m=col][d = c*32 + quad*8 + j] ----
    bf16x8 qh[2], ql[2];
    {
        const int s_row = row0 + wave * 16 + col;
        const float* qp = q + headQK + (size_t)s_row * D + quad * 8;
#pragma unroll
        for (int c = 0; c < 2; ++c) {
            fx4 a = *(const fx4*)(qp + c * 32);
            fx4 b = *(const fx4*)(qp + c * 32 + 4);
            float f[8] = {a[0],a[1],a[2],a[3],b[0],b[1],b[2],b[3]};
#pragma unroll
            for (int j = 0; j < 8; ++j) {
                short hi = f2bf(f[j]);
                qh[c][j] = hi;
                ql[c][j] = f2bf(f[j] - bf2f(hi));
            }
        }
    }

    fx4 U[4];   // U[nt] : C-layout, row = quad*4+reg, d = nt*16+col
#pragma unroll
    for (int nt = 0; nt < 4; ++nt) { U[nt][0]=0.f; U[nt][1]=0.f; U[nt][2]=0.f; U[nt][3]=0.f; }
    float rs_acc[4] = {0.f, 0.f, 0.f, 0.f};
    float T_acc[4]  = {0.f, 0.f, 0.f, 0.f};

    const float* kbase0 = k + headQK;
    const float* vbase0 = v + headQK;
    const float* ombase = om + headM + (size_t)(row0 + wave * 16) * S;

    for (int t0 = 0; t0 < S; t0 += BN) {
        __syncthreads();
        // ---- stage K -> ldsKh/ldsKl [t][d], V -> ldsVT [d][t] (bf16) ----
        {
            const float* kb = kbase0 + (size_t)t0 * D;
            const float* vb = vbase0 + (size_t)t0 * D;
#pragma unroll
            for (int i = 0; i < 4; ++i) {
                int g  = tid + i * 256;       // 0..1023
                int t  = g >> 4;              // 0..63
                int d4 = (g & 15) << 2;       // 0..60
                fx4 kv = *(const fx4*)(kb + (size_t)t * D + d4);
                fx4 vv = *(const fx4*)(vb + (size_t)t * D + d4);
                short4v k4h, k4l;
#pragma unroll
                for (int j = 0; j < 4; ++j) {
                    short hi = f2bf(kv[j]);
                    k4h[j] = hi;
                    k4l[j] = f2bf(kv[j] - bf2f(hi));
                }
                *(short4v*)(&ldsKh[t * KP + d4]) = k4h;
                *(short4v*)(&ldsKl[t * KP + d4]) = k4l;
                ldsVT[(d4 + 0) * KP + t] = f2bf(vv[0]);
                ldsVT[(d4 + 1) * KP + t] = f2bf(vv[1]);
                ldsVT[(d4 + 2) * KP + t] = f2bf(vv[2]);
                ldsVT[(d4 + 3) * KP + t] = f2bf(vv[3]);
            }
        }
        __syncthreads();

        // ---- scores (split precision): S = qh*kh + qh*kl + ql*kh ----
        fx4 Sc[4];
#pragma unroll
        for (int tn = 0; tn < 4; ++tn) {
            const short* kph = &ldsKh[(tn * 16 + col) * KP + quad * 8];
            const short* kpl = &ldsKl[(tn * 16 + col) * KP + quad * 8];
            bf16x8 kh0 = *(const bf16x8*)(kph);
            bf16x8 kh1 = *(const bf16x8*)(kph + 32);
            bf16x8 kl0 = *(const bf16x8*)(kpl);
            bf16x8 kl1 = *(const bf16x8*)(kpl + 32);
            fx4 z; z[0]=0.f; z[1]=0.f; z[2]=0.f; z[3]=0.f;
            z = __builtin_amdgcn_mfma_f32_16x16x32_bf16(qh[0], kh0, z, 0, 0, 0);
            z = __builtin_amdgcn_mfma_f32_16x16x32_bf16(qh[1], kh1, z, 0, 0, 0);
            z = __builtin_amdgcn_mfma_f32_16x16x32_bf16(qh[0], kl0, z, 0, 0, 0);
            z = __builtin_amdgcn_mfma_f32_16x16x32_bf16(qh[1], kl1, z, 0, 0, 0);
            z = __builtin_amdgcn_mfma_f32_16x16x32_bf16(ql[0], kh0, z, 0, 0, 0);
            z = __builtin_amdgcn_mfma_f32_16x16x32_bf16(ql[1], kh1, z, 0, 0, 0);
            Sc[tn] = z;
        }

        // ---- omask loads (C-layout: row = quad*4+r, col = tn*16+col) ----
        const float* omp = ombase + t0;
        float omv[4][4];
#pragma unroll
        for (int tn = 0; tn < 4; ++tn)
#pragma unroll
            for (int r = 0; r < 4; ++r)
                omv[tn][r] = omp[(size_t)(quad * 4 + r) * S + tn * 16 + col];

        // ---- P = S*om; accumulate rs, T (fp32); spill P (bf16) to wave-private LDS ----
#pragma unroll
        for (int tn = 0; tn < 4; ++tn) {
#pragma unroll
            for (int r = 0; r < 4; ++r) {
                float m = omv[tn][r];
                float p = Sc[tn][r] * m;
                rs_acc[r] += m;
                T_acc[r]  += p;
                ldsP[(wave * 16 + quad * 4 + r) * KP + tn * 16 + col] = f2bf(p);
            }
        }

        // ---- PV: out += P @ V (A-layout P from LDS, B-layout V^T from LDS) ----
#pragma unroll
        for (int kt = 0; kt < 2; ++kt) {
            bf16x8 pa = *(const bf16x8*)(&ldsP[(wave * 16 + col) * KP + kt * 32 + quad * 8]);
#pragma unroll
            for (int nt = 0; nt < 4; ++nt) {
                bf16x8 vb = *(const bf16x8*)(&ldsVT[(nt * 16 + col) * KP + kt * 32 + quad * 8]);
                U[nt] = __builtin_amdgcn_mfma_f32_16x16x32_bf16(pa, vb, U[nt], 0, 0, 0);
            }
        }
    }

    // ---- epilogue: reduce rs/T over the 16 lanes of each quad-row, scale, store ----
#pragma unroll
    for (int off = 1; off < 16; off <<= 1) {
#pragma unroll
        for (int r = 0; r < 4; ++r) {
            rs_acc[r] += __shfl_xor(rs_acc[r], off, 64);
            T_acc[r]  += __shfl_xor(T_acc[r], off, 64);
        }
    }
    float factor[4];
#pragma unroll
    for (int r = 0; r < 4; ++r) {
        float rs  = rs_acc[r];
        float inv = rs > 0.f ? rsqrtf(rs) : 0.f;
        float rowsum = T_acc[r] * inv;
        float sc = fabsf(rowsum);
        sc = sc < 1.f ? 1.f : sc;
        factor[r] = inv / sc;
    }
    float* op = out + headQK + (size_t)(row0 + wave * 16) * D;
#pragma unroll
    for (int r = 0; r < 4; ++r)
#pragma unroll
        for (int nt = 0; nt < 4; ++nt)
            op[(size_t)(quad * 4 + r) * D + nt * 16 + col] = U[nt][r] * factor[r];
}

extern "C" void kernel_launch(void* const* d_in, const int* in_sizes, int n_in,
                              void* d_out, int out_size, void* d_ws, size_t ws_size,
                              hipStream_t stream) {
    const float* q  = (const float*)d_in[0];
    const float* k  = (const float*)d_in[1];
    const float* v  = (const float*)d_in[2];
    const float* om = (const float*)d_in[3];
    float* out = (float*)d_out;
    (void)in_sizes; (void)n_in; (void)out_size; (void)d_ws; (void)ws_size;

    dim3 grid(H * (S / BM));   // 16 * 32 = 512 blocks
    dim3 block(256);
    hipLaunchKernelGGL(ParallelRetention_origin_25374666785438_kernel,
                       grid, block, 0, stream, q, k, v, om, out);
}

// Round 4
// 407.088 us; speedup vs baseline: 1.1547x; 1.1547x over previous
//
#include <hip/hip_runtime.h>

#define H 16
#define S 2048
#define D 64
#define BM 64            // q-rows per block (16 per wave)
#define BN 64            // t per tile
#define NT (S / BN)      // 32 tiles
#define KP 72            // LDS row pitch in bf16 elems (64+8 pad; 144B rows, 16B-aligned)

typedef __attribute__((ext_vector_type(8))) short bf16x8;
typedef __attribute__((ext_vector_type(4))) short short4v;
typedef __attribute__((ext_vector_type(4))) float fx4;

// fp32 -> bf16 bits, round-to-nearest-even
static __device__ __forceinline__ short f2bf(float x) {
    unsigned u = __float_as_uint(x);
    u += 0x7fffu + ((u >> 16) & 1u);
    return (short)(u >> 16);
}
static __device__ __forceinline__ float bf2f(short s) {
    return __uint_as_float(((unsigned)(unsigned short)s) << 16);
}

__global__ __launch_bounds__(256)
void ParallelRetention_origin_25374666785438_kernel(
    const float* __restrict__ q, const float* __restrict__ k,
    const float* __restrict__ v, const float* __restrict__ om,
    float* __restrict__ out)
{
    // double-buffered K(hi/lo) and V^T tiles + wave-private P round-trip
    __shared__ short ldsKh[2][BN * KP];
    __shared__ short ldsKl[2][BN * KP];
    __shared__ short ldsVT[2][BN * KP];
    __shared__ short ldsP[4 * 16 * KP];   // total LDS = 64512 B

    const int tid  = threadIdx.x;
    const int wave = tid >> 6;
    const int lane = tid & 63;
    const int col  = lane & 15;   // MFMA n-index / A-operand m-index
    const int quad = lane >> 4;   // 0..3
    // staging assignment: each thread owns 4 t-rows x 4 d-cols
    const int t_base = (tid >> 4) << 2;   // 0,4,..,60
    const int d4     = (tid & 15) << 2;   // 0,4,..,60

    const int h  = blockIdx.x & 15;      // consecutive blocks -> different heads
    const int qb = blockIdx.x >> 4;      // 0..31
    const int row0 = qb * BM;

    const size_t headQK = (size_t)h * S * D;
    const size_t headM  = (size_t)h * S * S;

    // ---- Q A-fragments once, hi/lo split: A[m=col][d = c*32 + quad*8 + j] ----
    bf16x8 qh[2], qlo[2];
    {
        const int s_row = row0 + wave * 16 + col;
        const float* qp = q + headQK + (size_t)s_row * D + quad * 8;
#pragma unroll
        for (int c = 0; c < 2; ++c) {
            fx4 a = *(const fx4*)(qp + c * 32);
            fx4 b = *(const fx4*)(qp + c * 32 + 4);
            float f[8] = {a[0],a[1],a[2],a[3],b[0],b[1],b[2],b[3]};
#pragma unroll
            for (int j = 0; j < 8; ++j) {
                short hi = f2bf(f[j]);
                qh[c][j]  = hi;
                qlo[c][j] = f2bf(f[j] - bf2f(hi));
            }
        }
    }

    fx4 U[4];   // C-layout: row = quad*4+reg, d = nt*16+col
#pragma unroll
    for (int nt = 0; nt < 4; ++nt) { U[nt][0]=0.f; U[nt][1]=0.f; U[nt][2]=0.f; U[nt][3]=0.f; }
    float rs_acc[4] = {0.f, 0.f, 0.f, 0.f};
    float T_acc[4]  = {0.f, 0.f, 0.f, 0.f};
    float om0[16], om1[16];   // omask double buffer (registers)

    const float* kbase0 = k + headQK;
    const float* vbase0 = v + headQK;
    const float* ombase = om + headM + (size_t)(row0 + wave * 16) * S;

    // ---- helpers (all force-inlined lambdas; arrays passed by reference) ----
    auto load_kv = [&](int t0, fx4 (&kr)[4], fx4 (&vr)[4]) {
        const float* kb = kbase0 + (size_t)t0 * D;
        const float* vb = vbase0 + (size_t)t0 * D;
#pragma unroll
        for (int r = 0; r < 4; ++r) {
            kr[r] = *(const fx4*)(kb + (size_t)(t_base + r) * D + d4);
            vr[r] = *(const fx4*)(vb + (size_t)(t_base + r) * D + d4);
        }
    };
    auto load_om = [&](int t0, float (&o)[16]) {
        const float* omp = ombase + t0;
#pragma unroll
        for (int tn = 0; tn < 4; ++tn)
#pragma unroll
            for (int r = 0; r < 4; ++r)
                o[tn * 4 + r] = omp[(size_t)(quad * 4 + r) * S + tn * 16 + col];
    };
    auto stage_write = [&](const fx4 (&kr)[4], const fx4 (&vr)[4],
                           short* Kh, short* Kl, short* VT) {
#pragma unroll
        for (int r = 0; r < 4; ++r) {       // K rows: contiguous b64, conflict-free
            short4v h4, l4;
#pragma unroll
            for (int j = 0; j < 4; ++j) {
                short hi = f2bf(kr[r][j]);
                h4[j] = hi;
                l4[j] = f2bf(kr[r][j] - bf2f(hi));
            }
            *(short4v*)(&Kh[(t_base + r) * KP + d4]) = h4;
            *(short4v*)(&Kl[(t_base + r) * KP + d4]) = l4;
        }
#pragma unroll
        for (int j = 0; j < 4; ++j) {       // V^T: 4 packed b64 (was 16 scalar u16)
            short4v p;
#pragma unroll
            for (int r = 0; r < 4; ++r) p[r] = f2bf(vr[r][j]);
            *(short4v*)(&VT[(d4 + j) * KP + t_base]) = p;
        }
    };
    auto compute = [&](const short* Kh, const short* Kl, const short* VT,
                       const float (&omc)[16]) {
#pragma unroll
        for (int tn = 0; tn < 4; ++tn) {
            const short* kph = &Kh[(tn * 16 + col) * KP + quad * 8];
            const short* kpl = &Kl[(tn * 16 + col) * KP + quad * 8];
            bf16x8 kh0 = *(const bf16x8*)(kph);
            bf16x8 kh1 = *(const bf16x8*)(kph + 32);
            bf16x8 kl0 = *(const bf16x8*)(kpl);
            bf16x8 kl1 = *(const bf16x8*)(kpl + 32);
            fx4 z; z[0]=0.f; z[1]=0.f; z[2]=0.f; z[3]=0.f;
            z = __builtin_amdgcn_mfma_f32_16x16x32_bf16(qh[0],  kh0, z, 0, 0, 0);
            z = __builtin_amdgcn_mfma_f32_16x16x32_bf16(qh[1],  kh1, z, 0, 0, 0);
            z = __builtin_amdgcn_mfma_f32_16x16x32_bf16(qh[0],  kl0, z, 0, 0, 0);
            z = __builtin_amdgcn_mfma_f32_16x16x32_bf16(qh[1],  kl1, z, 0, 0, 0);
            z = __builtin_amdgcn_mfma_f32_16x16x32_bf16(qlo[0], kh0, z, 0, 0, 0);
            z = __builtin_amdgcn_mfma_f32_16x16x32_bf16(qlo[1], kh1, z, 0, 0, 0);
#pragma unroll
            for (int r = 0; r < 4; ++r) {
                float m = omc[tn * 4 + r];
                float p = z[r] * m;
                rs_acc[r] += m;
                T_acc[r]  += p;
                ldsP[(wave * 16 + quad * 4 + r) * KP + tn * 16 + col] = f2bf(p);
            }
        }
#pragma unroll
        for (int kt = 0; kt < 2; ++kt) {
            bf16x8 pa = *(const bf16x8*)(&ldsP[(wave * 16 + col) * KP + kt * 32 + quad * 8]);
#pragma unroll
            for (int nt = 0; nt < 4; ++nt) {
                bf16x8 vb = *(const bf16x8*)(&VT[(nt * 16 + col) * KP + kt * 32 + quad * 8]);
                U[nt] = __builtin_amdgcn_mfma_f32_16x16x32_bf16(pa, vb, U[nt], 0, 0, 0);
            }
        }
    };

    // ---- prologue: stage tile 0, omask tile 0 ----
    {
        fx4 kr[4], vr[4];
        load_kv(0, kr, vr);
        load_om(0, om0);
        stage_write(kr, vr, ldsKh[0], ldsKl[0], ldsVT[0]);
    }

    // ---- pipelined main loop: barrier; issue t+1 globals; compute t; write t+1 ----
    for (int it2 = 0; it2 < NT; it2 += 2) {
        {   // even step: cur = buf0, omc = om0; prefetch (it2+1) into buf1/om1
            __syncthreads();
            fx4 kr[4], vr[4];
            load_kv((it2 + 1) * BN, kr, vr);     // it2+1 <= 31 always valid
            load_om((it2 + 1) * BN, om1);
            compute(ldsKh[0], ldsKl[0], ldsVT[0], om0);
            stage_write(kr, vr, ldsKh[1], ldsKl[1], ldsVT[1]);
        }
        {   // odd step: cur = buf1, omc = om1; prefetch (it2+2) into buf0/om0
            __syncthreads();
            const bool pf = (it2 + 2 < NT);
            fx4 kr[4], vr[4];
            if (pf) {
                load_kv((it2 + 2) * BN, kr, vr);
                load_om((it2 + 2) * BN, om0);
            }
            compute(ldsKh[1], ldsKl[1], ldsVT[1], om1);
            if (pf) stage_write(kr, vr, ldsKh[0], ldsKl[0], ldsVT[0]);
        }
    }

    // ---- epilogue: reduce rs/T across the 16 lanes of each quad-row, scale, store ----
#pragma unroll
    for (int off = 1; off < 16; off <<= 1) {
#pragma unroll
        for (int r = 0; r < 4; ++r) {
            rs_acc[r] += __shfl_xor(rs_acc[r], off, 64);
            T_acc[r]  += __shfl_xor(T_acc[r], off, 64);
        }
    }
    float factor[4];
#pragma unroll
    for (int r = 0; r < 4; ++r) {
        float rs  = rs_acc[r];
        float inv = rs > 0.f ? rsqrtf(rs) : 0.f;
        float rowsum = T_acc[r] * inv;
        float sc = fabsf(rowsum);
        sc = sc < 1.f ? 1.f : sc;
        factor[r] = inv / sc;
    }
    float* op = out + headQK + (size_t)(row0 + wave * 16) * D;
#pragma unroll
    for (int r = 0; r < 4; ++r)
#pragma unroll
        for (int nt = 0; nt < 4; ++nt)
            op[(size_t)(quad * 4 + r) * D + nt * 16 + col] = U[nt][r] * factor[r];
}

extern "C" void kernel_launch(void* const* d_in, const int* in_sizes, int n_in,
                              void* d_out, int out_size, void* d_ws, size_t ws_size,
                              hipStream_t stream) {
    const float* q  = (const float*)d_in[0];
    const float* k  = (const float*)d_in[1];
    const float* v  = (const float*)d_in[2];
    const float* om = (const float*)d_in[3];
    float* out = (float*)d_out;
    (void)in_sizes; (void)n_in; (void)out_size; (void)d_ws; (void)ws_size;

    dim3 grid(H * (S / BM));   // 512 blocks
    dim3 block(256);
    hipLaunchKernelGGL(ParallelRetention_origin_25374666785438_kernel,
                       grid, block, 0, stream, q, k, v, om, out);
}